// Round 1
// baseline (177.732 us; speedup 1.0000x reference)
//
#include <hip/hip_runtime.h>
#include <hip/hip_bf16.h>

typedef __bf16 bf16;
typedef __bf16 bf16x4 __attribute__((ext_vector_type(4)));
typedef __bf16 bf16x8 __attribute__((ext_vector_type(8)));
typedef float  f32x4  __attribute__((ext_vector_type(4)));

#define NEG_INF (-1e9f)

// Problem constants (from reference): B=2048 scenes, A=64 agents, D=128, H=4, HD=32
#define N_SCENES 2048
// w_in: [384][128] = 49152 elems ; w_out: [128][128] = 16384 elems

// ---------------------------------------------------------------------------
// Prep: block 0 computes exclusive prefix sum of agents_per_sample (B=2048);
// blocks 1..64 convert w_in / w_out fp32 -> bf16 into workspace.
// ---------------------------------------------------------------------------
__global__ __launch_bounds__(256) void prep_kernel(
    const float* __restrict__ w_in, const float* __restrict__ w_out,
    const int* __restrict__ agents,
    bf16* __restrict__ w_in_b, bf16* __restrict__ w_out_b, int* __restrict__ offs)
{
    __shared__ int tot[256];
    const int t = threadIdx.x;
    if (blockIdx.x == 0) {
        int loc[8]; int s = 0;
        #pragma unroll
        for (int j = 0; j < 8; ++j) { loc[j] = agents[t * 8 + j]; s += loc[j]; }
        tot[t] = s;
        __syncthreads();
        for (int o = 1; o < 256; o <<= 1) {
            int v = (t >= o) ? tot[t - o] : 0;
            __syncthreads();
            tot[t] += v;
            __syncthreads();
        }
        int run = tot[t] - s;   // exclusive base for this thread's chunk
        #pragma unroll
        for (int j = 0; j < 8; ++j) { offs[t * 8 + j] = run; run += loc[j]; }
    } else {
        int i = (blockIdx.x - 1) * 1024 + t * 4;   // 64 blocks * 1024 = 65536 = 49152 + 16384
        float4 v; bf16* dst;
        if (i < 49152) { v = *(const float4*)(w_in + i);            dst = w_in_b + i; }
        else           { v = *(const float4*)(w_out + (i - 49152)); dst = w_out_b + (i - 49152); }
        bf16x4 o = { (bf16)v.x, (bf16)v.y, (bf16)v.z, (bf16)v.w };
        *(bf16x4*)dst = o;
    }
}

// ---------------------------------------------------------------------------
// Fused attention: one block (4 waves) per scene.
// LDS: s_x 16KB (reused as per-wave P buffers) + s_qk 32KB + s_vT 16KB + s_ctx 16KB = 80KB
//      -> 2 blocks/CU.
// All LDS tiles use XOR swizzle on 16-byte chunks: chunk' = chunk ^ (row & mask),
// preserving 16B alignment for ds_read_b128 while avoiding bank conflicts.
// MFMA layouts (HW-verified, cdna_hip_programming.md §3):
//   A[m=lane&15][k=(lane>>4)*8 + j]  (8 contiguous k)
//   B[k=(lane>>4)*8 + j][n=lane&15]  (8 contiguous k, fixed col)
//   C/D: col=lane&15, row=(lane>>4)*4 + reg
// ---------------------------------------------------------------------------
__global__ __launch_bounds__(256, 2) void attn_kernel(
    const float* __restrict__ att_in,
    const float* __restrict__ b_in, const float* __restrict__ b_out,
    const bf16* __restrict__ w_in_b, const bf16* __restrict__ w_out_b,
    const int* __restrict__ agents, const int* __restrict__ offs,
    float* __restrict__ out)
{
    __shared__ bf16 s_x[64 * 128];    // x (stage1); reused as P buffers (4 x 4KB) in stage2
    __shared__ bf16 s_qk[64 * 256];   // q cols 0..127, k cols 128..255, row = agent
    __shared__ bf16 s_vT[128 * 64];   // v transposed: row = hd(0..127 across heads), col = agent
    __shared__ bf16 s_ctx[64 * 128];  // attention output, row-major

    const int b    = blockIdx.x;
    const int tid  = threadIdx.x;
    const int lane = tid & 63;
    const int w    = tid >> 6;        // wave id 0..3
    const int r    = lane & 15;
    const int qd   = lane >> 4;       // quad 0..3
    const int nb   = agents[b];
    const int off  = offs[b];

    // ---- stage 0: masked gather of x into LDS (bf16, swizzled) ----
    for (int i = tid; i < 64 * 32; i += 256) {
        int row = i >> 5, c4 = i & 31;            // c4 = float4 index within row (128 floats)
        float4 v = make_float4(0.f, 0.f, 0.f, 0.f);
        if (row < nb)
            v = *(const float4*)(att_in + (((size_t)(off + row)) << 7) + (c4 << 2));
        int chunk = c4 >> 1, half = c4 & 1;
        int c = chunk ^ (row & 15);
        bf16x4 o = { (bf16)v.x, (bf16)v.y, (bf16)v.z, (bf16)v.w };
        *(bf16x4*)(s_x + row * 128 + c * 8 + half * 4) = o;
    }
    __syncthreads();

    // ---- stage 1: QKV = x @ w_in^T + b_in ----
    // A-frags of x: held for the whole stage (16 frags = 64 VGPRs)
    bf16x8 xa[4][4];
    #pragma unroll
    for (int mt = 0; mt < 4; ++mt)
        #pragma unroll
        for (int ks = 0; ks < 4; ++ks) {
            int row = mt * 16 + r;
            int c = (ks * 4 + qd) ^ r;
            xa[mt][ks] = *(const bf16x8*)(s_x + row * 128 + c * 8);
        }
    #pragma unroll
    for (int t6 = 0; t6 < 6; ++t6) {
        int nt = w + t6 * 4;                       // n-tile 0..23 (j = nt*16 .. +15)
        int j0 = nt * 16;
        bf16x8 wb[4];
        #pragma unroll
        for (int ks = 0; ks < 4; ++ks)
            wb[ks] = *(const bf16x8*)(w_in_b + (size_t)(j0 + r) * 128 + ks * 32 + qd * 8);
        float bias = b_in[j0 + r];
        #pragma unroll
        for (int mt = 0; mt < 4; ++mt) {
            f32x4 acc = { 0.f, 0.f, 0.f, 0.f };
            #pragma unroll
            for (int ks = 0; ks < 4; ++ks)
                acc = __builtin_amdgcn_mfma_f32_16x16x32_bf16(xa[mt][ks], wb[ks], acc, 0, 0, 0);
            if (nt < 16) {
                // q/k region: row-major write (col = j0 + r)
                #pragma unroll
                for (int i = 0; i < 4; ++i) {
                    int row = mt * 16 + qd * 4 + i;
                    int c = (nt * 2 + (r >> 3)) ^ (row & 15);
                    s_qk[row * 256 + c * 8 + (r & 7)] = (bf16)(acc[i] + bias);
                }
            } else {
                // v region: transposed write, vT[hd][agent]
                int hd = j0 + r - 256;
                #pragma unroll
                for (int i = 0; i < 4; ++i) {
                    int agent = mt * 16 + qd * 4 + i;
                    int c = (agent >> 3) ^ (hd & 7);
                    s_vT[hd * 64 + c * 8 + (agent & 7)] = (bf16)(acc[i] + bias);
                }
            }
        }
    }
    __syncthreads();

    // ---- stage 2: attention, one head per wave ----
    const int h = w;
    bf16x8 qa[4], kb[4];
    #pragma unroll
    for (int mt = 0; mt < 4; ++mt) {
        int row = mt * 16 + r;
        int c = (h * 4 + qd) ^ (row & 15);
        qa[mt] = *(const bf16x8*)(s_qk + row * 256 + c * 8);
    }
    #pragma unroll
    for (int nt = 0; nt < 4; ++nt) {
        int row = nt * 16 + r;
        int c = (16 + h * 4 + qd) ^ (row & 15);
        kb[nt] = *(const bf16x8*)(s_qk + row * 256 + c * 8);
    }
    f32x4 S[4][4];
    #pragma unroll
    for (int mt = 0; mt < 4; ++mt)
        #pragma unroll
        for (int nt = 0; nt < 4; ++nt) {
            f32x4 z = { 0.f, 0.f, 0.f, 0.f };
            S[mt][nt] = __builtin_amdgcn_mfma_f32_16x16x32_bf16(qa[mt], kb[nt], z, 0, 0, 0);
        }

    // masked softmax over keys (cols), fully in registers
    const float scale = 0.17677669529663687f;      // 1/sqrt(32)
    bool kvalid[4];
    #pragma unroll
    for (int nt = 0; nt < 4; ++nt) kvalid[nt] = (nt * 16 + r) < nb;
    #pragma unroll
    for (int mt = 0; mt < 4; ++mt)
        #pragma unroll
        for (int i = 0; i < 4; ++i) {
            float v[4]; float mx = -3e38f;
            #pragma unroll
            for (int nt = 0; nt < 4; ++nt) {
                float val = kvalid[nt] ? S[mt][nt][i] * scale : NEG_INF;
                v[nt] = val; mx = fmaxf(mx, val);
            }
            mx = fmaxf(mx, __shfl_xor(mx, 1));
            mx = fmaxf(mx, __shfl_xor(mx, 2));
            mx = fmaxf(mx, __shfl_xor(mx, 4));
            mx = fmaxf(mx, __shfl_xor(mx, 8));
            float l = 0.f;
            #pragma unroll
            for (int nt = 0; nt < 4; ++nt) { v[nt] = __expf(v[nt] - mx); l += v[nt]; }
            l += __shfl_xor(l, 1); l += __shfl_xor(l, 2);
            l += __shfl_xor(l, 4); l += __shfl_xor(l, 8);
            float rl = 1.0f / l;
            #pragma unroll
            for (int nt = 0; nt < 4; ++nt) S[mt][nt][i] = v[nt] * rl;
        }

    // PV: round-trip P through per-wave LDS buffer (reuses dead s_x region), two K=32 halves
    bf16* Pbuf = s_x + w * 2048;                   // 64 rows x 32 cols bf16 = 4KB
    bf16x8 vb[2][2];
    #pragma unroll
    for (int ks = 0; ks < 2; ++ks)
        #pragma unroll
        for (int n2 = 0; n2 < 2; ++n2) {
            int hdr = h * 32 + n2 * 16 + r;
            int c = (ks * 4 + qd) ^ (hdr & 7);
            vb[ks][n2] = *(const bf16x8*)(s_vT + hdr * 64 + c * 8);
        }
    f32x4 cacc[4][2];
    #pragma unroll
    for (int mt = 0; mt < 4; ++mt)
        #pragma unroll
        for (int n2 = 0; n2 < 2; ++n2)
            cacc[mt][n2] = (f32x4){ 0.f, 0.f, 0.f, 0.f };
    #pragma unroll
    for (int hk = 0; hk < 2; ++hk) {
        // write P columns hk*32 .. hk*32+31 (tiles 2*hk, 2*hk+1)
        #pragma unroll
        for (int mt = 0; mt < 4; ++mt)
            #pragma unroll
            for (int n2 = 0; n2 < 2; ++n2)
                #pragma unroll
                for (int i = 0; i < 4; ++i) {
                    int row = mt * 16 + qd * 4 + i;
                    int col = n2 * 16 + r;
                    int c = (col >> 3) ^ (row & 3);
                    Pbuf[row * 32 + c * 8 + (col & 7)] = (bf16)S[mt][hk * 2 + n2][i];
                }
        bf16x8 pa[4];
        #pragma unroll
        for (int mt = 0; mt < 4; ++mt) {
            int row = mt * 16 + r;
            int c = qd ^ (row & 3);
            pa[mt] = *(const bf16x8*)(Pbuf + row * 32 + c * 8);
        }
        #pragma unroll
        for (int mt = 0; mt < 4; ++mt)
            #pragma unroll
            for (int n2 = 0; n2 < 2; ++n2)
                cacc[mt][n2] = __builtin_amdgcn_mfma_f32_16x16x32_bf16(
                                   pa[mt], vb[hk][n2], cacc[mt][n2], 0, 0, 0);
    }
    // ctx -> LDS (row-major, swizzled)
    #pragma unroll
    for (int mt = 0; mt < 4; ++mt)
        #pragma unroll
        for (int n2 = 0; n2 < 2; ++n2)
            #pragma unroll
            for (int i = 0; i < 4; ++i) {
                int row = mt * 16 + qd * 4 + i;
                int col = h * 32 + n2 * 16 + r;
                int c = (col >> 3) ^ (row & 15);
                s_ctx[row * 128 + c * 8 + (col & 7)] = (bf16)cacc[mt][n2][i];
            }
    __syncthreads();

    // ---- stage 3: out = (ctx @ w_out^T + b_out) * row_mask ----
    bf16x8 ca[4][4];
    #pragma unroll
    for (int mt = 0; mt < 4; ++mt)
        #pragma unroll
        for (int ks = 0; ks < 4; ++ks) {
            int row = mt * 16 + r;
            int c = (ks * 4 + qd) ^ (row & 15);
            ca[mt][ks] = *(const bf16x8*)(s_ctx + row * 128 + c * 8);
        }
    #pragma unroll
    for (int t2 = 0; t2 < 2; ++t2) {
        int nt = w * 2 + t2;                       // 0..7
        int j0 = nt * 16;
        bf16x8 wb[4];
        #pragma unroll
        for (int ks = 0; ks < 4; ++ks)
            wb[ks] = *(const bf16x8*)(w_out_b + (size_t)(j0 + r) * 128 + ks * 32 + qd * 8);
        float bias = b_out[j0 + r];
        #pragma unroll
        for (int mt = 0; mt < 4; ++mt) {
            f32x4 acc = { 0.f, 0.f, 0.f, 0.f };
            #pragma unroll
            for (int ks = 0; ks < 4; ++ks)
                acc = __builtin_amdgcn_mfma_f32_16x16x32_bf16(ca[mt][ks], wb[ks], acc, 0, 0, 0);
            #pragma unroll
            for (int i = 0; i < 4; ++i) {
                int row = mt * 16 + qd * 4 + i;
                float val = (row < nb) ? (acc[i] + bias) : 0.f;
                out[((size_t)b * 64 + row) * 128 + j0 + r] = val;
            }
        }
    }
}

extern "C" void kernel_launch(void* const* d_in, const int* in_sizes, int n_in,
                              void* d_out, int out_size, void* d_ws, size_t ws_size,
                              hipStream_t stream)
{
    const float* att_in = (const float*)d_in[0];
    const float* w_in   = (const float*)d_in[1];
    const float* b_in   = (const float*)d_in[2];
    const float* w_out  = (const float*)d_in[3];
    const float* b_out  = (const float*)d_in[4];
    const int*   agents = (const int*)d_in[5];

    bf16* w_in_b  = (bf16*)d_ws;                        // 49152 * 2B
    bf16* w_out_b = w_in_b + 49152;                     // 16384 * 2B
    int*  offs    = (int*)((char*)d_ws + 98304 + 32768);// 2048 * 4B

    prep_kernel<<<65, 256, 0, stream>>>(w_in, w_out, agents, w_in_b, w_out_b, offs);
    attn_kernel<<<N_SCENES, 256, 0, stream>>>(att_in, b_in, b_out, w_in_b, w_out_b,
                                              agents, offs, (float*)d_out);
}